// Round 15
// baseline (620.490 us; speedup 1.0000x reference)
//
#include <hip/hip_runtime.h>
#include <stdint.h>

typedef __attribute__((ext_vector_type(8))) short short8;
typedef __attribute__((ext_vector_type(4))) float f32x4;
typedef __attribute__((ext_vector_type(2))) unsigned int u32x2;
typedef unsigned short u16;
typedef unsigned int u32;

#define NPER 6
// frag-major weight regions (bf16 element offsets). Each frag = 512 elems = 1KB,
// lane-major: frag[lane][j] = W[n(frag,lane)][k(frag,lane,j)].   (identical to R10/R11/R14)
#define SA_F   0
#define CRW_F  131072
#define CW1_F  196608
#define CW2_F  262144
#define TRW_F  266240
#define TW1_F  331776
#define TW2_F  397312
#define WS_WELE 401408   // h16 follows

__device__ inline u16 f2b(float f){                 // f32 -> bf16 (RNE) -- converter kernels only
  u32 u = __builtin_bit_cast(u32, f);
  u = u + 0x7FFFu + ((u >> 16) & 1u);
  return (u16)(u >> 16);
}
__device__ inline float elu1(float x){ return x > 0.f ? x : (__expf(x) - 1.f); }
// HW packed f32x2 -> bf16x2 (RNE; bit-identical to f2b -- verified R13/R14 absmax)
__device__ inline u32 cvtpk(float a, float b){
  u32 r;
  asm("v_cvt_pk_bf16_f32 %0, %1, %2" : "=v"(r) : "v"(a), "v"(b));
  return r;
}

// ---- frag-major weight conversion (identical to R10/R14) ----
__global__ __launch_bounds__(256) void convert_weights(
    const float* __restrict__ sw, const float* __restrict__ crw, const float* __restrict__ cw1,
    const float* __restrict__ cw2, const float* __restrict__ trw, const float* __restrict__ tw1,
    const float* __restrict__ tw2, u16* __restrict__ ws){
  int i = blockIdx.x * 256 + threadIdx.x;
  if (i >= WS_WELE) return;
  int e = i & 511;
  int lane = e >> 3, j = e & 7, lr = lane & 15, lg = lane >> 4;
  float v;
  if (i < CRW_F){        int fs = i >> 9;              int n = (fs & 15) * 16 + lr, k = (fs >> 4) * 32 + lg * 8 + j; v = sw[n * 512 + k]; }
  else if (i < CW1_F){   int fs = (i - CRW_F) >> 9;    int n = (fs & 15) * 16 + lr, k = (fs >> 4) * 32 + lg * 8 + j; v = crw[n * 256 + k]; }
  else if (i < CW2_F){   int fs = (i - CW1_F) >> 9;    int n = (fs & 15) * 16 + lr, k = (fs >> 4) * 32 + lg * 8 + j; v = cw1[n * 256 + k]; }
  else if (i < TRW_F){   int fs = (i - CW2_F) >> 9;    int k = fs * 32 + lg * 8 + j; v = (lr < NPER) ? cw2[lr * 256 + k] : 0.f; }
  else if (i < TW1_F){   int fs = (i - TRW_F) >> 9;    int n = (fs & 15) * 16 + lr, k = (fs >> 4) * 32 + lg * 8 + j; v = trw[n * 256 + k]; }
  else if (i < TW2_F){   int fs = (i - TW1_F) >> 9;    int n = (fs & 15) * 16 + lr, k = (fs >> 4) * 32 + lg * 8 + j; v = tw1[n * 256 + k]; }
  else {                 int fs = (i - TW2_F) >> 9;    int k = fs * 32 + lg * 8 + j; v = (lr < NPER) ? tw2[lr * 256 + k] : 0.f; }
  ws[i] = f2b(v);
}

__global__ __launch_bounds__(256) void convert_h(
    const float* __restrict__ h, u16* __restrict__ h16, int n8){
  int i = blockIdx.x * 256 + threadIdx.x;
  if (i >= n8) return;
  const float4* src = (const float4*)(h + (size_t)i * 8);
  float4 q0 = src[0], q1 = src[1];
  short8 v;
  v[0]=(short)f2b(q0.x); v[1]=(short)f2b(q0.y); v[2]=(short)f2b(q0.z); v[3]=(short)f2b(q0.w);
  v[4]=(short)f2b(q1.x); v[5]=(short)f2b(q1.y); v[6]=(short)f2b(q1.z); v[7]=(short)f2b(q1.w);
  *(short8*)(h16 + (size_t)i * 8) = v;
}

// ---- in-kernel macros ----
#define WF(D_, BASE_, FS_) { D_ = ((const short8*)(ws + (BASE_) + (size_t)(FS_) * 512))[lane]; }
#define WF4(D_, BASE_, KS_) { WF(D_##0, BASE_, (KS_)*16 + fq + 0); WF(D_##1, BASE_, (KS_)*16 + fq + 1); \
                              WF(D_##2, BASE_, (KS_)*16 + fq + 2); WF(D_##3, BASE_, (KS_)*16 + fq + 3); }
#define LDA4(D_, SRC_, RS_, KB_) { const int ao_ = ((KB_) + lg * 16) ^ aswz; \
  _Pragma("unroll") for (int af_ = 0; af_ < 4; ++af_){ \
    const int r_ = af_ * 16 + lr; \
    D_[af_] = *(const short8*)((SRC_) + r_ * (RS_) + ao_); } }
#define GEMM16(W_, A_) { __builtin_amdgcn_s_setprio(1); \
  _Pragma("unroll") for (int af_ = 0; af_ < 4; ++af_){ \
    acc[0][af_] = __builtin_amdgcn_mfma_f32_16x16x32_bf16(W_##0, A_[af_], acc[0][af_], 0, 0, 0); \
    acc[1][af_] = __builtin_amdgcn_mfma_f32_16x16x32_bf16(W_##1, A_[af_], acc[1][af_], 0, 0, 0); \
    acc[2][af_] = __builtin_amdgcn_mfma_f32_16x16x32_bf16(W_##2, A_[af_], acc[2][af_], 0, 0, 0); \
    acc[3][af_] = __builtin_amdgcn_mfma_f32_16x16x32_bf16(W_##3, A_[af_], acc[3][af_], 0, 0, 0); } \
  __builtin_amdgcn_s_setprio(0); }
#define ZERO_ACC() { _Pragma("unroll") for (int i_ = 0; i_ < 4; ++i_) \
  _Pragma("unroll") for (int j_ = 0; j_ < 4; ++j_) acc[i_][j_] = (f32x4){0.f,0.f,0.f,0.f}; }
#define BAR() { asm volatile("s_waitcnt lgkmcnt(0)" ::: "memory"); \
  __builtin_amdgcn_sched_barrier(0); \
  __builtin_amdgcn_s_barrier(); \
  __builtin_amdgcn_sched_barrier(0); }
#define LOADC(c) { const int c_ = (c); \
  int nd_ = ((c_>>1)==0)?idx4.x:((c_>>1)==1)?idx4.y:((c_>>1)==2)?idx4.z:idx4.w; \
  const size_t o_ = (size_t)nd_ * 128 + (c_ & 1) * 64 + sq * 16; \
  if (H16){ rgA = *(const short8*)(h16 + o_); rgB = *(const short8*)(h16 + o_ + 8); } \
  else { float4 qa_=*(const float4*)(h+o_), qb_=*(const float4*)(h+o_+4); \
         float4 qc_=*(const float4*)(h+o_+8), qd_=*(const float4*)(h+o_+12); \
    u32 tA_[4] = { cvtpk(qa_.x,qa_.y), cvtpk(qa_.z,qa_.w), cvtpk(qb_.x,qb_.y), cvtpk(qb_.z,qb_.w) }; \
    u32 tB_[4] = { cvtpk(qc_.x,qc_.y), cvtpk(qc_.z,qc_.w), cvtpk(qd_.x,qd_.y), cvtpk(qd_.z,qd_.w) }; \
    rgA = *(short8*)tA_; rgB = *(short8*)tB_; } }
#define STOREC(c) { char* b_ = Zb + (((c) & 1) << 13) + srow * 128; const int sw_ = (srow & 7) << 4; \
  *(short8*)(b_ + ((sq * 32) ^ sw_))      = rgA; \
  *(short8*)(b_ + ((sq * 32 + 16) ^ sw_)) = rgB; }

// ---- 3-set rotation (2-deep prefetch; S_ is always a compile-time constant) ----
#define WF4R(S_, BASE_) { if (((S_) % 3) == 0){ WF4(wfA, BASE_, S_); } \
  else if (((S_) % 3) == 1){ WF4(wfB, BASE_, S_); } else { WF4(wfC, BASE_, S_); } }
#define GEMMW(S_, A_) { if (((S_) % 3) == 0){ GEMM16(wfA, A_); } \
  else if (((S_) % 3) == 1){ GEMM16(wfB, A_); } else { GEMM16(wfC, A_); } }
#define LDA4R(S_, SRC_) { if (((S_) % 3) == 0){ LDA4(afA, SRC_, 512, (S_) * 64); } \
  else if (((S_) % 3) == 1){ LDA4(afB, SRC_, 512, (S_) * 64); } else { LDA4(afC, SRC_, 512, (S_) * 64); } }
#define GEMMR(S_) { if (((S_) % 3) == 0){ GEMM16(wfA, afA); } \
  else if (((S_) % 3) == 1){ GEMM16(wfB, afB); } else { GEMM16(wfC, afC); } }

// one 256-k layer, 8 k-steps, 2-deep W/A prefetch (3 rotating sets), no internal barriers
#define LAYER256(WBASE_, AB_) { \
  WF4R(0, WBASE_); LDA4R(0, AB_); \
  WF4R(1, WBASE_); LDA4R(1, AB_); \
  _Pragma("unroll") for (int ks_ = 0; ks_ < 8; ++ks_){ \
    if (ks_ < 6){ WF4R(ks_ + 2, WBASE_); LDA4R(ks_ + 2, AB_); } \
    GEMMR(ks_); } }

template<bool H16>
__global__ __launch_bounds__(256) void torsion_kernel(
    const float* __restrict__ h, const u16* __restrict__ h16,
    const int* __restrict__ idxs, const float* __restrict__ sb,
    const float* __restrict__ c_rb, const float* __restrict__ c_b1, const float* __restrict__ c_b2,
    const float* __restrict__ t_rb, const float* __restrict__ t_b1, const float* __restrict__ t_b2,
    const u16* __restrict__ ws, float* __restrict__ out, int NT)
{
  __shared__ __attribute__((aligned(16))) char Xb[32768];   // [64][256] bf16 swizzled
  __shared__ __attribute__((aligned(16))) char Zb[32768];   // gather dbuf 2x8KB, then Y/V

  const int tid = threadIdx.x, blk = blockIdx.x;
  const int lane = tid & 63, lr = lane & 15, lg = lane >> 4;
  const int wv = tid >> 6;                     // wave 0..3 = col quarter
  const int fq = wv * 4;
  const int aswz = (lr & 7) << 4;

  const int srow = tid >> 2, sq = tid & 3;
  const int sgrow = blk * 64 + srow;
  int4 idx4 = (sgrow < NT) ? ((const int4*)idxs)[sgrow] : (int4){0, 0, 0, 0};
  short8 rgA, rgB;
  short8 wfA0, wfA1, wfA2, wfA3, wfB0, wfB1, wfB2, wfB3, wfC0, wfC1, wfC2, wfC3;
  short8 afA[4], afB[4], afC[4];

  f32x4 acc[4][4];
  ZERO_ACC();

  // ---- prologue: gather chunk 0 staged; W k-steps 0,1 in flight ----
  LOADC(0); STOREC(0);
  WF4R(0, SA_F);
  WF4R(1, SA_F);
  BAR();
  LDA4(afA, Zb, 128, 0);

  // ================ stage A: x = elu(concat(h[idx]) @ sw.T + sb); 8 chunks ================
  // global k-steps s = 2c + kk; W rotates A/B/C 2-deep; A-frags use afA (post-bar) / afB (in-chunk)
  #pragma unroll
  for (int c = 0; c < 8; ++c){
    const char* cb = Zb + ((c & 1) << 13);
    if (c < 7) LOADC(c + 1);
    LDA4(afB, cb, 128, 64);
    if (2 * c + 2 < 16) WF4R(2 * c + 2, SA_F);
    GEMMW(2 * c, afA);
    if (2 * c + 3 < 16) WF4R(2 * c + 3, SA_F);
    GEMMW(2 * c + 1, afB);
    if (c < 7) STOREC(c + 1);
    if (c == 7){
      // X epilogue: elu + bias -> Xb (swizzled bf16)
      #pragma unroll
      for (int wf = 0; wf < 4; ++wf){
        const int col0 = wv * 64 + wf * 16 + lg * 4;
        const float4 bb = *(const float4*)(sb + col0);
        #pragma unroll
        for (int af = 0; af < 4; ++af){
          const int row = af * 16 + lr;
          u32x2 pk = { cvtpk(elu1(acc[wf][af][0] + bb.x), elu1(acc[wf][af][1] + bb.y)),
                       cvtpk(elu1(acc[wf][af][2] + bb.z), elu1(acc[wf][af][3] + bb.w)) };
          *(u32x2*)(Xb + row * 512 + ((col0 * 2) ^ ((row & 7) << 4))) = pk;
        }
      }
    }
    BAR();
    if (c < 7) LDA4(afA, Zb + (((c + 1) & 1) << 13), 128, 0);
  }

  // ================ heads: c (score) then t (coeffs) ================
  f32x4 scC = (f32x4){0,0,0,0}, scT = (f32x4){0,0,0,0};
  #pragma unroll
  for (int hd = 0; hd < 2; ++hd){
    const int RWF = hd ? TRW_F : CRW_F;
    const int W1F = hd ? TW1_F : CW1_F;
    const int W2F = hd ? TW2_F : CW2_F;
    const float* RB = hd ? t_rb : c_rb;
    const float* B1 = hd ? t_b1 : c_b1;
    const float* B2 = hd ? t_b2 : c_b2;

    // ---- y = x + elu(x @ rw.T + rb) -> Zb  (residual re-read from Xb) ----
    ZERO_ACC();
    LAYER256(RWF, Xb);
    #pragma unroll
    for (int wf = 0; wf < 4; ++wf){
      const int col0 = wv * 64 + wf * 16 + lg * 4;
      const float4 bb = *(const float4*)(RB + col0);
      #pragma unroll
      for (int af = 0; af < 4; ++af){
        const int row = af * 16 + lr;
        const int boff = (col0 * 2) ^ ((row & 7) << 4);
        u32x2 xv = *(const u32x2*)(Xb + row * 512 + boff);
        const float x0 = __builtin_bit_cast(float, xv[0] << 16);
        const float x1 = __builtin_bit_cast(float, xv[0] & 0xffff0000u);
        const float x2 = __builtin_bit_cast(float, xv[1] << 16);
        const float x3 = __builtin_bit_cast(float, xv[1] & 0xffff0000u);
        u32x2 pk = { cvtpk(x0 + elu1(acc[wf][af][0] + bb.x), x1 + elu1(acc[wf][af][1] + bb.y)),
                     cvtpk(x2 + elu1(acc[wf][af][2] + bb.z), x3 + elu1(acc[wf][af][3] + bb.w)) };
        *(u32x2*)(Zb + row * 512 + boff) = pk;
      }
    }
    BAR();                                  // Y visible

    // ---- v = elu(y @ w1.T + b1): layer, drain-bar, V epilogue -> Zb ----
    ZERO_ACC();
    LAYER256(W1F, Zb);
    BAR();                                  // all Y reads done before overwrite
    #pragma unroll
    for (int wf = 0; wf < 4; ++wf){
      const int col0 = wv * 64 + wf * 16 + lg * 4;
      const float4 bb = *(const float4*)(B1 + col0);
      #pragma unroll
      for (int af = 0; af < 4; ++af){
        const int row = af * 16 + lr;
        u32x2 pk = { cvtpk(elu1(acc[wf][af][0] + bb.x), elu1(acc[wf][af][1] + bb.y)),
                     cvtpk(elu1(acc[wf][af][2] + bb.z), elu1(acc[wf][af][3] + bb.w)) };
        *(u32x2*)(Zb + row * 512 + ((col0 * 2) ^ ((row & 7) << 4))) = pk;
      }
    }
    BAR();                                  // V visible

    // ---- out16 = v @ w2p.T: wave wv owns rows wv*16..+15 ----
    {
      f32x4 a1 = (f32x4){0, 0, 0, 0};
      const int vr = wv * 16 + lr;
      const int vswz = (vr & 7) << 4;
      __builtin_amdgcn_s_setprio(1);
      #pragma unroll
      for (int kt = 0; kt < 8; ++kt){
        short8 aw; WF(aw, W2F, kt);
        short8 bv = *(const short8*)(Zb + vr * 512 + ((kt * 64 + lg * 16) ^ vswz));
        a1 = __builtin_amdgcn_mfma_f32_16x16x32_bf16(aw, bv, a1, 0, 0, 0);
      }
      __builtin_amdgcn_s_setprio(0);
      #pragma unroll
      for (int r = 0; r < 4; ++r){
        const int nn = lg * 4 + r;
        a1[r] += (nn < NPER) ? B2[nn] : 0.f;
      }
      if (hd == 0) scC = a1; else scT = a1;
      BAR();                                // w2's V reads done before head t's Y overwrites
    }
  }

  // ---- epilogue: score & coeff for row (wv*16+lr) live in this lane ----
  const int grow = blk * 64 + wv * 16 + lr;
  if (grow < NT){
    #pragma unroll
    for (int r = 0; r < 4; ++r){
      const int nn = lg * 4 + r;
      if (nn < NPER){
        const float s = scC[r], c = scT[r];
        out[(size_t)grow * 6 + nn] = s;
        out[(size_t)NT * 6 + (size_t)grow * 6 + nn] = c * 1e-3f * (1.f / (1.f + __expf(-s)));
      }
    }
  }
}

extern "C" void kernel_launch(void* const* d_in, const int* in_sizes, int n_in,
                              void* d_out, int out_size, void* d_ws, size_t ws_size,
                              hipStream_t stream){
  const float* h    = (const float*)d_in[0];
  const int*   idxs = (const int*)d_in[1];
  const float* sw   = (const float*)d_in[2];
  const float* sb   = (const float*)d_in[3];
  const float* trw  = (const float*)d_in[4];
  const float* trb  = (const float*)d_in[5];
  const float* tw1  = (const float*)d_in[6];
  const float* tb1  = (const float*)d_in[7];
  const float* tw2  = (const float*)d_in[8];
  const float* tb2  = (const float*)d_in[9];
  const float* crw  = (const float*)d_in[10];
  const float* crb  = (const float*)d_in[11];
  const float* cw1  = (const float*)d_in[12];
  const float* cb1  = (const float*)d_in[13];
  const float* cw2  = (const float*)d_in[14];
  const float* cb2  = (const float*)d_in[15];
  u16* ws    = (u16*)d_ws;
  float* out = (float*)d_out;
  const int NT = in_sizes[1] / 4;
  const int nh = in_sizes[0];
  const bool useH16 = ws_size >= (size_t)(WS_WELE + nh) * 2;

  hipLaunchKernelGGL(convert_weights, dim3((WS_WELE + 255) / 256), dim3(256), 0, stream,
                     sw, crw, cw1, cw2, trw, tw1, tw2, ws);
  u16* h16 = ws + WS_WELE;
  const int nblk = (NT + 63) / 64;
  if (useH16){
    const int n8 = nh / 8;
    hipLaunchKernelGGL(convert_h, dim3((n8 + 255) / 256), dim3(256), 0, stream, h, h16, n8);
    torsion_kernel<true><<<dim3(nblk), dim3(256), 0, stream>>>(
        h, h16, idxs, sb, crb, cb1, cb2, trb, tb1, tb2, ws, out, NT);
  } else {
    torsion_kernel<false><<<dim3(nblk), dim3(256), 0, stream>>>(
        h, h16, idxs, sb, crb, cb1, cb2, trb, tb1, tb2, ws, out, NT);
  }
}

// Round 16
// 478.337 us; speedup vs baseline: 1.2972x; 1.2972x over previous
//
#include <hip/hip_runtime.h>
#include <stdint.h>

typedef __attribute__((ext_vector_type(8))) short short8;
typedef __attribute__((ext_vector_type(4))) float f32x4;
typedef __attribute__((ext_vector_type(2))) unsigned int u32x2;
typedef unsigned short u16;
typedef unsigned int u32;

#define NPER 6
// frag-major weight regions (bf16 element offsets). Each frag = 512 elems = 1KB,
// lane-major: frag[lane][j] = W[n(frag,lane)][k(frag,lane,j)].   (identical to R10/R11/R14)
#define SA_F   0
#define CRW_F  131072
#define CW1_F  196608
#define CW2_F  262144
#define TRW_F  266240
#define TW1_F  331776
#define TW2_F  397312
#define WS_WELE 401408   // h16 follows

__device__ inline u16 f2b(float f){                 // f32 -> bf16 (RNE) -- converter kernels only
  u32 u = __builtin_bit_cast(u32, f);
  u = u + 0x7FFFu + ((u >> 16) & 1u);
  return (u16)(u >> 16);
}
__device__ inline float elu1(float x){ return x > 0.f ? x : (__expf(x) - 1.f); }
// HW packed f32x2 -> bf16x2 (RNE; bit-identical to f2b -- verified R13/R14 absmax)
__device__ inline u32 cvtpk(float a, float b){
  u32 r;
  asm("v_cvt_pk_bf16_f32 %0, %1, %2" : "=v"(r) : "v"(a), "v"(b));
  return r;
}

// ---- frag-major weight conversion (identical to R10/R14) ----
__global__ __launch_bounds__(256) void convert_weights(
    const float* __restrict__ sw, const float* __restrict__ crw, const float* __restrict__ cw1,
    const float* __restrict__ cw2, const float* __restrict__ trw, const float* __restrict__ tw1,
    const float* __restrict__ tw2, u16* __restrict__ ws){
  int i = blockIdx.x * 256 + threadIdx.x;
  if (i >= WS_WELE) return;
  int e = i & 511;
  int lane = e >> 3, j = e & 7, lr = lane & 15, lg = lane >> 4;
  float v;
  if (i < CRW_F){        int fs = i >> 9;              int n = (fs & 15) * 16 + lr, k = (fs >> 4) * 32 + lg * 8 + j; v = sw[n * 512 + k]; }
  else if (i < CW1_F){   int fs = (i - CRW_F) >> 9;    int n = (fs & 15) * 16 + lr, k = (fs >> 4) * 32 + lg * 8 + j; v = crw[n * 256 + k]; }
  else if (i < CW2_F){   int fs = (i - CW1_F) >> 9;    int n = (fs & 15) * 16 + lr, k = (fs >> 4) * 32 + lg * 8 + j; v = cw1[n * 256 + k]; }
  else if (i < TRW_F){   int fs = (i - CW2_F) >> 9;    int k = fs * 32 + lg * 8 + j; v = (lr < NPER) ? cw2[lr * 256 + k] : 0.f; }
  else if (i < TW1_F){   int fs = (i - TRW_F) >> 9;    int n = (fs & 15) * 16 + lr, k = (fs >> 4) * 32 + lg * 8 + j; v = trw[n * 256 + k]; }
  else if (i < TW2_F){   int fs = (i - TW1_F) >> 9;    int n = (fs & 15) * 16 + lr, k = (fs >> 4) * 32 + lg * 8 + j; v = tw1[n * 256 + k]; }
  else {                 int fs = (i - TW2_F) >> 9;    int k = fs * 32 + lg * 8 + j; v = (lr < NPER) ? tw2[lr * 256 + k] : 0.f; }
  ws[i] = f2b(v);
}

__global__ __launch_bounds__(256) void convert_h(
    const float* __restrict__ h, u16* __restrict__ h16, int n8){
  int i = blockIdx.x * 256 + threadIdx.x;
  if (i >= n8) return;
  const float4* src = (const float4*)(h + (size_t)i * 8);
  float4 q0 = src[0], q1 = src[1];
  short8 v;
  v[0]=(short)f2b(q0.x); v[1]=(short)f2b(q0.y); v[2]=(short)f2b(q0.z); v[3]=(short)f2b(q0.w);
  v[4]=(short)f2b(q1.x); v[5]=(short)f2b(q1.y); v[6]=(short)f2b(q1.z); v[7]=(short)f2b(q1.w);
  *(short8*)(h16 + (size_t)i * 8) = v;
}

// ---- in-kernel macros (R14 base) ----
#define WF(D_, BASE_, FS_) { D_ = ((const short8*)(ws + (BASE_) + (size_t)(FS_) * 512))[lane]; }
#define WF4(D_, BASE_, KS_) { WF(D_##0, BASE_, (KS_)*16 + fq + 0); WF(D_##1, BASE_, (KS_)*16 + fq + 1); \
                              WF(D_##2, BASE_, (KS_)*16 + fq + 2); WF(D_##3, BASE_, (KS_)*16 + fq + 3); }
#define LDA4(D_, SRC_, RS_, KB_) { const int ao_ = ((KB_) + lg * 16) ^ aswz; \
  _Pragma("unroll") for (int af_ = 0; af_ < 4; ++af_){ \
    const int r_ = af_ * 16 + lr; \
    D_[af_] = *(const short8*)((SRC_) + r_ * (RS_) + ao_); } }
#define GEMM16(W_, A_) { __builtin_amdgcn_s_setprio(1); \
  _Pragma("unroll") for (int af_ = 0; af_ < 4; ++af_){ \
    acc[0][af_] = __builtin_amdgcn_mfma_f32_16x16x32_bf16(W_##0, A_[af_], acc[0][af_], 0, 0, 0); \
    acc[1][af_] = __builtin_amdgcn_mfma_f32_16x16x32_bf16(W_##1, A_[af_], acc[1][af_], 0, 0, 0); \
    acc[2][af_] = __builtin_amdgcn_mfma_f32_16x16x32_bf16(W_##2, A_[af_], acc[2][af_], 0, 0, 0); \
    acc[3][af_] = __builtin_amdgcn_mfma_f32_16x16x32_bf16(W_##3, A_[af_], acc[3][af_], 0, 0, 0); } \
  __builtin_amdgcn_s_setprio(0); }
#define ZERO_ACC() { _Pragma("unroll") for (int i_ = 0; i_ < 4; ++i_) \
  _Pragma("unroll") for (int j_ = 0; j_ < 4; ++j_) acc[i_][j_] = (f32x4){0.f,0.f,0.f,0.f}; }
#define BAR() { asm volatile("s_waitcnt lgkmcnt(0)" ::: "memory"); \
  __builtin_amdgcn_sched_barrier(0); \
  __builtin_amdgcn_s_barrier(); \
  __builtin_amdgcn_sched_barrier(0); }

// ---- paired-node gather staging: one full node (128 feats, 16KB) per barrier ----
// thread (srow 0..63, sq 0..3) covers feats sq*32..+31 (64B) of its row
#define LOADC2(sc) { const int sc_ = (sc); \
  int nd_ = (sc_==0)?idx4.x:(sc_==1)?idx4.y:(sc_==2)?idx4.z:idx4.w; \
  if (H16){ const u16* p_ = h16 + (size_t)nd_ * 128 + sq * 32; \
    rgA = *(const short8*)(p_);      rgB = *(const short8*)(p_ + 8); \
    rgC = *(const short8*)(p_ + 16); rgD = *(const short8*)(p_ + 24); } \
  else { const float* fp_ = h + (size_t)nd_ * 128 + sq * 32; \
    float4 qa_=*(const float4*)fp_,      qb_=*(const float4*)(fp_+4); \
    float4 qc_=*(const float4*)(fp_+8),  qd_=*(const float4*)(fp_+12); \
    float4 qe_=*(const float4*)(fp_+16), qf_=*(const float4*)(fp_+20); \
    float4 qg_=*(const float4*)(fp_+24), qh_=*(const float4*)(fp_+28); \
    u32 tA_[4] = { cvtpk(qa_.x,qa_.y), cvtpk(qa_.z,qa_.w), cvtpk(qb_.x,qb_.y), cvtpk(qb_.z,qb_.w) }; \
    u32 tB_[4] = { cvtpk(qc_.x,qc_.y), cvtpk(qc_.z,qc_.w), cvtpk(qd_.x,qd_.y), cvtpk(qd_.z,qd_.w) }; \
    u32 tC_[4] = { cvtpk(qe_.x,qe_.y), cvtpk(qe_.z,qe_.w), cvtpk(qf_.x,qf_.y), cvtpk(qf_.z,qf_.w) }; \
    u32 tD_[4] = { cvtpk(qg_.x,qg_.y), cvtpk(qg_.z,qg_.w), cvtpk(qh_.x,qh_.y), cvtpk(qh_.z,qh_.w) }; \
    rgA = *(short8*)tA_; rgB = *(short8*)tB_; rgC = *(short8*)tC_; rgD = *(short8*)tD_; } }
// dest: half (sc&1)*16KB; chunk lo/hi (sq>>1)*8KB; [64][64] rows 128B, XOR-swizzled
#define STOREC2(sc) { char* b_ = Zb + (((sc) & 1) << 14) + (sq >> 1) * 8192 + srow * 128; \
  const int o_ = (sq & 1) * 64, sw_ = (srow & 7) << 4; \
  *(short8*)(b_ + ((o_     ) ^ sw_)) = rgA; \
  *(short8*)(b_ + ((o_ + 16) ^ sw_)) = rgB; \
  *(short8*)(b_ + ((o_ + 32) ^ sw_)) = rgC; \
  *(short8*)(b_ + ((o_ + 48) ^ sw_)) = rgD; }

// one 256-k layer, 8 k-steps, W/A 1-deep prefetch, no internal barriers (R14)
#define LAYER256(WBASE_, AB_) { \
  WF4(wfA, WBASE_, 0); \
  LDA4(afA, AB_, 512, 0); \
  _Pragma("unroll") for (int ks_ = 0; ks_ < 8; ++ks_){ \
    if (ks_ & 1){ \
      if (ks_ < 7){ WF4(wfA, WBASE_, ks_ + 1); LDA4(afA, AB_, 512, (ks_ + 1) * 64); } \
      GEMM16(wfB, afB); \
    } else { \
      WF4(wfB, WBASE_, ks_ + 1); LDA4(afB, AB_, 512, (ks_ + 1) * 64); \
      GEMM16(wfA, afA); \
    } } }

template<bool H16>
__global__ __launch_bounds__(256) void torsion_kernel(
    const float* __restrict__ h, const u16* __restrict__ h16,
    const int* __restrict__ idxs, const float* __restrict__ sb,
    const float* __restrict__ c_rb, const float* __restrict__ c_b1, const float* __restrict__ c_b2,
    const float* __restrict__ t_rb, const float* __restrict__ t_b1, const float* __restrict__ t_b2,
    const u16* __restrict__ ws, float* __restrict__ out, int NT)
{
  __shared__ __attribute__((aligned(16))) char Xb[32768];   // [64][256] bf16 swizzled
  __shared__ __attribute__((aligned(16))) char Zb[32768];   // gather dbuf 2x16KB, then Y/V

  const int tid = threadIdx.x, blk = blockIdx.x;
  const int lane = tid & 63, lr = lane & 15, lg = lane >> 4;
  const int wv = tid >> 6;                     // wave 0..3 = col quarter
  const int fq = wv * 4;
  const int aswz = (lr & 7) << 4;

  const int srow = tid >> 2, sq = tid & 3;
  const int sgrow = blk * 64 + srow;
  int4 idx4 = (sgrow < NT) ? ((const int4*)idxs)[sgrow] : (int4){0, 0, 0, 0};
  short8 rgA, rgB, rgC, rgD;
  short8 wfA0, wfA1, wfA2, wfA3, wfB0, wfB1, wfB2, wfB3;
  short8 afA[4], afB[4];

  f32x4 acc[4][4];
  ZERO_ACC();

  // ---- prologue: node 0 staged; first W frags in flight ----
  LOADC2(0); STOREC2(0);
  WF4(wfA, SA_F, 0);
  BAR();
  LDA4(afA, Zb, 128, 0);

  // ================ stage A: x = elu(concat(h[idx]) @ sw.T + sb); 4 node-superchunks ================
  // k-steps s = 4*sc + {0..3}; chunk lo = k 0..63, hi = k 64..127 of node sc
  #pragma unroll
  for (int sc = 0; sc < 4; ++sc){
    const char* cb = Zb + ((sc & 1) << 14);
    if (sc < 3) LOADC2(sc + 1);                      // next node's loads in flight all interval
    WF4(wfB, SA_F, 4 * sc + 1); LDA4(afB, cb, 128, 64);
    GEMM16(wfA, afA);                                // s = 4sc
    WF4(wfA, SA_F, 4 * sc + 2); LDA4(afA, cb + 8192, 128, 0);
    GEMM16(wfB, afB);                                // s = 4sc+1
    WF4(wfB, SA_F, 4 * sc + 3); LDA4(afB, cb + 8192, 128, 64);
    GEMM16(wfA, afA);                                // s = 4sc+2
    if (sc < 3) WF4(wfA, SA_F, 4 * sc + 4);
    GEMM16(wfB, afB);                                // s = 4sc+3
    if (sc < 3) STOREC2(sc + 1);
    if (sc == 3){
      // X epilogue: elu + bias -> Xb (swizzled bf16)
      #pragma unroll
      for (int wf = 0; wf < 4; ++wf){
        const int col0 = wv * 64 + wf * 16 + lg * 4;
        const float4 bb = *(const float4*)(sb + col0);
        #pragma unroll
        for (int af = 0; af < 4; ++af){
          const int row = af * 16 + lr;
          u32x2 pk = { cvtpk(elu1(acc[wf][af][0] + bb.x), elu1(acc[wf][af][1] + bb.y)),
                       cvtpk(elu1(acc[wf][af][2] + bb.z), elu1(acc[wf][af][3] + bb.w)) };
          *(u32x2*)(Xb + row * 512 + ((col0 * 2) ^ ((row & 7) << 4))) = pk;
        }
      }
    }
    BAR();
    if (sc < 3) LDA4(afA, Zb + (((sc + 1) & 1) << 14), 128, 0);
  }

  // ================ heads: c (score) then t (coeffs) ================
  f32x4 scC = (f32x4){0,0,0,0}, scT = (f32x4){0,0,0,0};
  #pragma unroll
  for (int hd = 0; hd < 2; ++hd){
    const int RWF = hd ? TRW_F : CRW_F;
    const int W1F = hd ? TW1_F : CW1_F;
    const int W2F = hd ? TW2_F : CW2_F;
    const float* RB = hd ? t_rb : c_rb;
    const float* B1 = hd ? t_b1 : c_b1;
    const float* B2 = hd ? t_b2 : c_b2;

    // ---- y = x + elu(x @ rw.T + rb) -> Zb  (residual re-read from Xb) ----
    ZERO_ACC();
    LAYER256(RWF, Xb);
    #pragma unroll
    for (int wf = 0; wf < 4; ++wf){
      const int col0 = wv * 64 + wf * 16 + lg * 4;
      const float4 bb = *(const float4*)(RB + col0);
      #pragma unroll
      for (int af = 0; af < 4; ++af){
        const int row = af * 16 + lr;
        const int boff = (col0 * 2) ^ ((row & 7) << 4);
        u32x2 xv = *(const u32x2*)(Xb + row * 512 + boff);
        const float x0 = __builtin_bit_cast(float, xv[0] << 16);
        const float x1 = __builtin_bit_cast(float, xv[0] & 0xffff0000u);
        const float x2 = __builtin_bit_cast(float, xv[1] << 16);
        const float x3 = __builtin_bit_cast(float, xv[1] & 0xffff0000u);
        u32x2 pk = { cvtpk(x0 + elu1(acc[wf][af][0] + bb.x), x1 + elu1(acc[wf][af][1] + bb.y)),
                     cvtpk(x2 + elu1(acc[wf][af][2] + bb.z), x3 + elu1(acc[wf][af][3] + bb.w)) };
        *(u32x2*)(Zb + row * 512 + boff) = pk;
      }
    }
    BAR();                                  // Y visible

    // ---- v = elu(y @ w1.T + b1): layer, drain-bar, V epilogue -> Zb ----
    ZERO_ACC();
    LAYER256(W1F, Zb);
    BAR();                                  // all Y reads done before overwrite
    #pragma unroll
    for (int wf = 0; wf < 4; ++wf){
      const int col0 = wv * 64 + wf * 16 + lg * 4;
      const float4 bb = *(const float4*)(B1 + col0);
      #pragma unroll
      for (int af = 0; af < 4; ++af){
        const int row = af * 16 + lr;
        u32x2 pk = { cvtpk(elu1(acc[wf][af][0] + bb.x), elu1(acc[wf][af][1] + bb.y)),
                     cvtpk(elu1(acc[wf][af][2] + bb.z), elu1(acc[wf][af][3] + bb.w)) };
        *(u32x2*)(Zb + row * 512 + ((col0 * 2) ^ ((row & 7) << 4))) = pk;
      }
    }
    BAR();                                  // V visible

    // ---- out16 = v @ w2p.T: wave wv owns rows wv*16..+15 ----
    {
      f32x4 a1 = (f32x4){0, 0, 0, 0};
      const int vr = wv * 16 + lr;
      const int vswz = (vr & 7) << 4;
      __builtin_amdgcn_s_setprio(1);
      #pragma unroll
      for (int kt = 0; kt < 8; ++kt){
        short8 aw; WF(aw, W2F, kt);
        short8 bv = *(const short8*)(Zb + vr * 512 + ((kt * 64 + lg * 16) ^ vswz));
        a1 = __builtin_amdgcn_mfma_f32_16x16x32_bf16(aw, bv, a1, 0, 0, 0);
      }
      __builtin_amdgcn_s_setprio(0);
      #pragma unroll
      for (int r = 0; r < 4; ++r){
        const int nn = lg * 4 + r;
        a1[r] += (nn < NPER) ? B2[nn] : 0.f;
      }
      if (hd == 0) scC = a1; else scT = a1;
      if (hd == 0) BAR();                   // protect Zb(V) before head t's Y-epilogue overwrite
    }
  }

  // ---- epilogue: score & coeff for row (wv*16+lr) live in this lane ----
  const int grow = blk * 64 + wv * 16 + lr;
  if (grow < NT){
    #pragma unroll
    for (int r = 0; r < 4; ++r){
      const int nn = lg * 4 + r;
      if (nn < NPER){
        const float s = scC[r], c = scT[r];
        out[(size_t)grow * 6 + nn] = s;
        out[(size_t)NT * 6 + (size_t)grow * 6 + nn] = c * 1e-3f * (1.f / (1.f + __expf(-s)));
      }
    }
  }
}

extern "C" void kernel_launch(void* const* d_in, const int* in_sizes, int n_in,
                              void* d_out, int out_size, void* d_ws, size_t ws_size,
                              hipStream_t stream){
  const float* h    = (const float*)d_in[0];
  const int*   idxs = (const int*)d_in[1];
  const float* sw   = (const float*)d_in[2];
  const float* sb   = (const float*)d_in[3];
  const float* trw  = (const float*)d_in[4];
  const float* trb  = (const float*)d_in[5];
  const float* tw1  = (const float*)d_in[6];
  const float* tb1  = (const float*)d_in[7];
  const float* tw2  = (const float*)d_in[8];
  const float* tb2  = (const float*)d_in[9];
  const float* crw  = (const float*)d_in[10];
  const float* crb  = (const float*)d_in[11];
  const float* cw1  = (const float*)d_in[12];
  const float* cb1  = (const float*)d_in[13];
  const float* cw2  = (const float*)d_in[14];
  const float* cb2  = (const float*)d_in[15];
  u16* ws    = (u16*)d_ws;
  float* out = (float*)d_out;
  const int NT = in_sizes[1] / 4;
  const int nh = in_sizes[0];
  const bool useH16 = ws_size >= (size_t)(WS_WELE + nh) * 2;

  hipLaunchKernelGGL(convert_weights, dim3((WS_WELE + 255) / 256), dim3(256), 0, stream,
                     sw, crw, cw1, cw2, trw, tw1, tw2, ws);
  u16* h16 = ws + WS_WELE;
  const int nblk = (NT + 63) / 64;
  if (useH16){
    const int n8 = nh / 8;
    hipLaunchKernelGGL(convert_h, dim3((n8 + 255) / 256), dim3(256), 0, stream, h, h16, n8);
    torsion_kernel<true><<<dim3(nblk), dim3(256), 0, stream>>>(
        h, h16, idxs, sb, crb, cb1, cb2, trb, tb1, tb2, ws, out, NT);
  } else {
    torsion_kernel<false><<<dim3(nblk), dim3(256), 0, stream>>>(
        h, h16, idxs, sb, crb, cb1, cb2, trb, tb1, tb2, ws, out, NT);
  }
}

// Round 17
// 458.626 us; speedup vs baseline: 1.3529x; 1.0430x over previous
//
#include <hip/hip_runtime.h>
#include <stdint.h>

typedef __attribute__((ext_vector_type(8))) short short8;
typedef __attribute__((ext_vector_type(4))) float f32x4;
typedef __attribute__((ext_vector_type(2))) unsigned int u32x2;
typedef unsigned short u16;
typedef unsigned int u32;

#define NPER 6
// frag-major weight regions (bf16 element offsets). Each frag = 512 elems = 1KB,
// lane-major: frag[lane][j] = W[n(frag,lane)][k(frag,lane,j)].   (identical to R10..R16)
#define SA_F   0
#define CRW_F  131072
#define CW1_F  196608
#define CW2_F  262144
#define TRW_F  266240
#define TW1_F  331776
#define TW2_F  397312
#define WS_WELE 401408   // h16 follows

__device__ inline u16 f2b(float f){                 // f32 -> bf16 (RNE) -- converter kernels only
  u32 u = __builtin_bit_cast(u32, f);
  u = u + 0x7FFFu + ((u >> 16) & 1u);
  return (u16)(u >> 16);
}
__device__ inline float elu1(float x){ return x > 0.f ? x : (__expf(x) - 1.f); }
// HW packed f32x2 -> bf16x2 (RNE; bit-identical to f2b -- verified R13/R14 absmax)
__device__ inline u32 cvtpk(float a, float b){
  u32 r;
  asm("v_cvt_pk_bf16_f32 %0, %1, %2" : "=v"(r) : "v"(a), "v"(b));
  return r;
}

// ---- frag-major weight conversion (identical to R10/R14) ----
__global__ __launch_bounds__(256) void convert_weights(
    const float* __restrict__ sw, const float* __restrict__ crw, const float* __restrict__ cw1,
    const float* __restrict__ cw2, const float* __restrict__ trw, const float* __restrict__ tw1,
    const float* __restrict__ tw2, u16* __restrict__ ws){
  int i = blockIdx.x * 256 + threadIdx.x;
  if (i >= WS_WELE) return;
  int e = i & 511;
  int lane = e >> 3, j = e & 7, lr = lane & 15, lg = lane >> 4;
  float v;
  if (i < CRW_F){        int fs = i >> 9;              int n = (fs & 15) * 16 + lr, k = (fs >> 4) * 32 + lg * 8 + j; v = sw[n * 512 + k]; }
  else if (i < CW1_F){   int fs = (i - CRW_F) >> 9;    int n = (fs & 15) * 16 + lr, k = (fs >> 4) * 32 + lg * 8 + j; v = crw[n * 256 + k]; }
  else if (i < CW2_F){   int fs = (i - CW1_F) >> 9;    int n = (fs & 15) * 16 + lr, k = (fs >> 4) * 32 + lg * 8 + j; v = cw1[n * 256 + k]; }
  else if (i < TRW_F){   int fs = (i - CW2_F) >> 9;    int k = fs * 32 + lg * 8 + j; v = (lr < NPER) ? cw2[lr * 256 + k] : 0.f; }
  else if (i < TW1_F){   int fs = (i - TRW_F) >> 9;    int n = (fs & 15) * 16 + lr, k = (fs >> 4) * 32 + lg * 8 + j; v = trw[n * 256 + k]; }
  else if (i < TW2_F){   int fs = (i - TW1_F) >> 9;    int n = (fs & 15) * 16 + lr, k = (fs >> 4) * 32 + lg * 8 + j; v = tw1[n * 256 + k]; }
  else {                 int fs = (i - TW2_F) >> 9;    int k = fs * 32 + lg * 8 + j; v = (lr < NPER) ? tw2[lr * 256 + k] : 0.f; }
  ws[i] = f2b(v);
}

__global__ __launch_bounds__(256) void convert_h(
    const float* __restrict__ h, u16* __restrict__ h16, int n8){
  int i = blockIdx.x * 256 + threadIdx.x;
  if (i >= n8) return;
  const float4* src = (const float4*)(h + (size_t)i * 8);
  float4 q0 = src[0], q1 = src[1];
  short8 v;
  v[0]=(short)f2b(q0.x); v[1]=(short)f2b(q0.y); v[2]=(short)f2b(q0.z); v[3]=(short)f2b(q0.w);
  v[4]=(short)f2b(q1.x); v[5]=(short)f2b(q1.y); v[6]=(short)f2b(q1.z); v[7]=(short)f2b(q1.w);
  *(short8*)(h16 + (size_t)i * 8) = v;
}

// ---- in-kernel macros (R16 base) ----
#define WF(D_, BASE_, FS_) { D_ = ((const short8*)(ws + (BASE_) + (size_t)(FS_) * 512))[lane]; }
#define WF4(D_, BASE_, KS_) { WF(D_##0, BASE_, (KS_)*16 + fq + 0); WF(D_##1, BASE_, (KS_)*16 + fq + 1); \
                              WF(D_##2, BASE_, (KS_)*16 + fq + 2); WF(D_##3, BASE_, (KS_)*16 + fq + 3); }
#define LDA4(D_, SRC_, RS_, KB_) { const int ao_ = ((KB_) + lg * 16) ^ aswz; \
  _Pragma("unroll") for (int af_ = 0; af_ < 4; ++af_){ \
    const int r_ = af_ * 16 + lr; \
    D_[af_] = *(const short8*)((SRC_) + r_ * (RS_) + ao_); } }
#define GEMM16(W_, A_) { __builtin_amdgcn_s_setprio(1); \
  _Pragma("unroll") for (int af_ = 0; af_ < 4; ++af_){ \
    acc[0][af_] = __builtin_amdgcn_mfma_f32_16x16x32_bf16(W_##0, A_[af_], acc[0][af_], 0, 0, 0); \
    acc[1][af_] = __builtin_amdgcn_mfma_f32_16x16x32_bf16(W_##1, A_[af_], acc[1][af_], 0, 0, 0); \
    acc[2][af_] = __builtin_amdgcn_mfma_f32_16x16x32_bf16(W_##2, A_[af_], acc[2][af_], 0, 0, 0); \
    acc[3][af_] = __builtin_amdgcn_mfma_f32_16x16x32_bf16(W_##3, A_[af_], acc[3][af_], 0, 0, 0); } \
  __builtin_amdgcn_s_setprio(0); }
// first-k-step variant: C = per-wf bias fragment (replaces zeroing + epilogue bias add)
#define GEMMB16(W_, A_) { __builtin_amdgcn_s_setprio(1); \
  _Pragma("unroll") for (int af_ = 0; af_ < 4; ++af_){ \
    acc[0][af_] = __builtin_amdgcn_mfma_f32_16x16x32_bf16(W_##0, A_[af_], bv[0], 0, 0, 0); \
    acc[1][af_] = __builtin_amdgcn_mfma_f32_16x16x32_bf16(W_##1, A_[af_], bv[1], 0, 0, 0); \
    acc[2][af_] = __builtin_amdgcn_mfma_f32_16x16x32_bf16(W_##2, A_[af_], bv[2], 0, 0, 0); \
    acc[3][af_] = __builtin_amdgcn_mfma_f32_16x16x32_bf16(W_##3, A_[af_], bv[3], 0, 0, 0); } \
  __builtin_amdgcn_s_setprio(0); }
#define LOADBIAS(BP_) { _Pragma("unroll") for (int wf_ = 0; wf_ < 4; ++wf_){ \
    float4 t_ = *(const float4*)((BP_) + wv * 64 + wf_ * 16 + lg * 4); \
    bv[wf_] = (f32x4){t_.x, t_.y, t_.z, t_.w}; } }
#define BAR() { asm volatile("s_waitcnt lgkmcnt(0)" ::: "memory"); \
  __builtin_amdgcn_sched_barrier(0); \
  __builtin_amdgcn_s_barrier(); \
  __builtin_amdgcn_sched_barrier(0); }

// ---- paired-node gather staging (R16): one full node (128 feats, 16KB) per barrier ----
#define LOADC2(sc) { const int sc_ = (sc); \
  int nd_ = (sc_==0)?idx4.x:(sc_==1)?idx4.y:(sc_==2)?idx4.z:idx4.w; \
  if (H16){ const u16* p_ = h16 + (size_t)nd_ * 128 + sq * 32; \
    rgA = *(const short8*)(p_);      rgB = *(const short8*)(p_ + 8); \
    rgC = *(const short8*)(p_ + 16); rgD = *(const short8*)(p_ + 24); } \
  else { const float* fp_ = h + (size_t)nd_ * 128 + sq * 32; \
    float4 qa_=*(const float4*)fp_,      qb_=*(const float4*)(fp_+4); \
    float4 qc_=*(const float4*)(fp_+8),  qd_=*(const float4*)(fp_+12); \
    float4 qe_=*(const float4*)(fp_+16), qf_=*(const float4*)(fp_+20); \
    float4 qg_=*(const float4*)(fp_+24), qh_=*(const float4*)(fp_+28); \
    u32 tA_[4] = { cvtpk(qa_.x,qa_.y), cvtpk(qa_.z,qa_.w), cvtpk(qb_.x,qb_.y), cvtpk(qb_.z,qb_.w) }; \
    u32 tB_[4] = { cvtpk(qc_.x,qc_.y), cvtpk(qc_.z,qc_.w), cvtpk(qd_.x,qd_.y), cvtpk(qd_.z,qd_.w) }; \
    u32 tC_[4] = { cvtpk(qe_.x,qe_.y), cvtpk(qe_.z,qe_.w), cvtpk(qf_.x,qf_.y), cvtpk(qf_.z,qf_.w) }; \
    u32 tD_[4] = { cvtpk(qg_.x,qg_.y), cvtpk(qg_.z,qg_.w), cvtpk(qh_.x,qh_.y), cvtpk(qh_.z,qh_.w) }; \
    rgA = *(short8*)tA_; rgB = *(short8*)tB_; rgC = *(short8*)tC_; rgD = *(short8*)tD_; } }
#define STOREC2(sc) { char* b_ = Zb + (((sc) & 1) << 14) + (sq >> 1) * 8192 + srow * 128; \
  const int o_ = (sq & 1) * 64, sw_ = (srow & 7) << 4; \
  *(short8*)(b_ + ((o_     ) ^ sw_)) = rgA; \
  *(short8*)(b_ + ((o_ + 16) ^ sw_)) = rgB; \
  *(short8*)(b_ + ((o_ + 32) ^ sw_)) = rgC; \
  *(short8*)(b_ + ((o_ + 48) ^ sw_)) = rgD; }

// one 256-k layer, 8 k-steps, W/A 1-deep prefetch; ks=0 initializes acc with bias (bv)
#define LAYER256B(WBASE_, AB_) { \
  WF4(wfA, WBASE_, 0); \
  LDA4(afA, AB_, 512, 0); \
  _Pragma("unroll") for (int ks_ = 0; ks_ < 8; ++ks_){ \
    if (ks_ & 1){ \
      if (ks_ < 7){ WF4(wfA, WBASE_, ks_ + 1); LDA4(afA, AB_, 512, (ks_ + 1) * 64); } \
      GEMM16(wfB, afB); \
    } else { \
      WF4(wfB, WBASE_, ks_ + 1); LDA4(afB, AB_, 512, (ks_ + 1) * 64); \
      if (ks_ == 0){ GEMMB16(wfA, afA); } else { GEMM16(wfA, afA); } \
    } } }

template<bool H16>
__global__ __launch_bounds__(256) void torsion_kernel(
    const float* __restrict__ h, const u16* __restrict__ h16,
    const int* __restrict__ idxs, const float* __restrict__ sb,
    const float* __restrict__ c_rb, const float* __restrict__ c_b1, const float* __restrict__ c_b2,
    const float* __restrict__ t_rb, const float* __restrict__ t_b1, const float* __restrict__ t_b2,
    const u16* __restrict__ ws, float* __restrict__ out, int NT)
{
  __shared__ __attribute__((aligned(16))) char Xb[32768];   // [64][256] bf16 swizzled
  __shared__ __attribute__((aligned(16))) char Zb[32768];   // gather dbuf 2x16KB, then Y/V

  const int tid = threadIdx.x, blk = blockIdx.x;
  const int lane = tid & 63, lr = lane & 15, lg = lane >> 4;
  const int wv = tid >> 6;                     // wave 0..3 = col quarter
  const int fq = wv * 4;
  const int aswz = (lr & 7) << 4;

  const int srow = tid >> 2, sq = tid & 3;
  const int sgrow = blk * 64 + srow;
  int4 idx4 = (sgrow < NT) ? ((const int4*)idxs)[sgrow] : (int4){0, 0, 0, 0};
  short8 rgA, rgB, rgC, rgD;
  short8 wfA0, wfA1, wfA2, wfA3, wfB0, wfB1, wfB2, wfB3;
  short8 afA[4], afB[4];
  f32x4 bv[4];                                 // bias C-fragments (transient per layer)

  f32x4 acc[4][4];

  // ---- prologue: node 0 staged; first W frags + sb bias in flight ----
  LOADC2(0); STOREC2(0);
  WF4(wfA, SA_F, 0);
  LOADBIAS(sb);
  BAR();
  LDA4(afA, Zb, 128, 0);

  // ================ stage A: x = elu(concat(h[idx]) @ sw.T + sb); 4 node-superchunks ================
  #pragma unroll
  for (int sc = 0; sc < 4; ++sc){
    const char* cb = Zb + ((sc & 1) << 14);
    if (sc < 3) LOADC2(sc + 1);                      // next node's loads in flight all interval
    WF4(wfB, SA_F, 4 * sc + 1); LDA4(afB, cb, 128, 64);
    if (sc == 0){ GEMMB16(wfA, afA); } else { GEMM16(wfA, afA); }   // s = 4sc (bias C-init at s=0)
    WF4(wfA, SA_F, 4 * sc + 2); LDA4(afA, cb + 8192, 128, 0);
    GEMM16(wfB, afB);                                // s = 4sc+1
    WF4(wfB, SA_F, 4 * sc + 3); LDA4(afB, cb + 8192, 128, 64);
    GEMM16(wfA, afA);                                // s = 4sc+2
    if (sc < 3) WF4(wfA, SA_F, 4 * sc + 4);
    GEMM16(wfB, afB);                                // s = 4sc+3
    if (sc < 3) STOREC2(sc + 1);
    if (sc == 3){
      // X epilogue: elu (bias already in acc) -> Xb (swizzled bf16)
      #pragma unroll
      for (int wf = 0; wf < 4; ++wf){
        const int col0 = wv * 64 + wf * 16 + lg * 4;
        #pragma unroll
        for (int af = 0; af < 4; ++af){
          const int row = af * 16 + lr;
          u32x2 pk = { cvtpk(elu1(acc[wf][af][0]), elu1(acc[wf][af][1])),
                       cvtpk(elu1(acc[wf][af][2]), elu1(acc[wf][af][3])) };
          *(u32x2*)(Xb + row * 512 + ((col0 * 2) ^ ((row & 7) << 4))) = pk;
        }
      }
    }
    BAR();
    if (sc < 3) LDA4(afA, Zb + (((sc + 1) & 1) << 14), 128, 0);
  }

  // ================ heads: c (score) then t (coeffs) ================
  f32x4 scC = (f32x4){0,0,0,0}, scT = (f32x4){0,0,0,0};
  #pragma unroll
  for (int hd = 0; hd < 2; ++hd){
    const int RWF = hd ? TRW_F : CRW_F;
    const int W1F = hd ? TW1_F : CW1_F;
    const int W2F = hd ? TW2_F : CW2_F;
    const float* RB = hd ? t_rb : c_rb;
    const float* B1 = hd ? t_b1 : c_b1;
    const float* B2 = hd ? t_b2 : c_b2;

    // ---- y = x + elu(x @ rw.T + rb) -> Zb  (rb via C-init; residual re-read from Xb) ----
    LOADBIAS(RB);
    LAYER256B(RWF, Xb);
    #pragma unroll
    for (int wf = 0; wf < 4; ++wf){
      const int col0 = wv * 64 + wf * 16 + lg * 4;
      #pragma unroll
      for (int af = 0; af < 4; ++af){
        const int row = af * 16 + lr;
        const int boff = (col0 * 2) ^ ((row & 7) << 4);
        u32x2 xv = *(const u32x2*)(Xb + row * 512 + boff);
        const float x0 = __builtin_bit_cast(float, xv[0] << 16);
        const float x1 = __builtin_bit_cast(float, xv[0] & 0xffff0000u);
        const float x2 = __builtin_bit_cast(float, xv[1] << 16);
        const float x3 = __builtin_bit_cast(float, xv[1] & 0xffff0000u);
        u32x2 pk = { cvtpk(x0 + elu1(acc[wf][af][0]), x1 + elu1(acc[wf][af][1])),
                     cvtpk(x2 + elu1(acc[wf][af][2]), x3 + elu1(acc[wf][af][3])) };
        *(u32x2*)(Zb + row * 512 + boff) = pk;
      }
    }
    BAR();                                  // Y visible

    // ---- v = elu(y @ w1.T + b1): layer (b1 via C-init), drain-bar, V epilogue -> Zb ----
    LOADBIAS(B1);
    LAYER256B(W1F, Zb);
    BAR();                                  // all Y reads done before overwrite
    #pragma unroll
    for (int wf = 0; wf < 4; ++wf){
      const int col0 = wv * 64 + wf * 16 + lg * 4;
      #pragma unroll
      for (int af = 0; af < 4; ++af){
        const int row = af * 16 + lr;
        u32x2 pk = { cvtpk(elu1(acc[wf][af][0]), elu1(acc[wf][af][1])),
                     cvtpk(elu1(acc[wf][af][2]), elu1(acc[wf][af][3])) };
        *(u32x2*)(Zb + row * 512 + ((col0 * 2) ^ ((row & 7) << 4))) = pk;
      }
    }
    BAR();                                  // V visible

    // ---- out16 = v @ w2p.T: wave wv owns rows wv*16..+15 ----
    {
      f32x4 a1 = (f32x4){0, 0, 0, 0};
      const int vr = wv * 16 + lr;
      const int vswz = (vr & 7) << 4;
      __builtin_amdgcn_s_setprio(1);
      #pragma unroll
      for (int kt = 0; kt < 8; ++kt){
        short8 aw; WF(aw, W2F, kt);
        short8 bv2 = *(const short8*)(Zb + vr * 512 + ((kt * 64 + lg * 16) ^ vswz));
        a1 = __builtin_amdgcn_mfma_f32_16x16x32_bf16(aw, bv2, a1, 0, 0, 0);
      }
      __builtin_amdgcn_s_setprio(0);
      #pragma unroll
      for (int r = 0; r < 4; ++r){
        const int nn = lg * 4 + r;
        a1[r] += (nn < NPER) ? B2[nn] : 0.f;
      }
      if (hd == 0) scC = a1; else scT = a1;
      if (hd == 0) BAR();                   // protect Zb(V) before head t's Y-epilogue overwrite
    }
  }

  // ---- epilogue: score & coeff for row (wv*16+lr) live in this lane ----
  const int grow = blk * 64 + wv * 16 + lr;
  if (grow < NT){
    #pragma unroll
    for (int r = 0; r < 4; ++r){
      const int nn = lg * 4 + r;
      if (nn < NPER){
        const float s = scC[r], c = scT[r];
        out[(size_t)grow * 6 + nn] = s;
        out[(size_t)NT * 6 + (size_t)grow * 6 + nn] = c * 1e-3f * (1.f / (1.f + __expf(-s)));
      }
    }
  }
}

extern "C" void kernel_launch(void* const* d_in, const int* in_sizes, int n_in,
                              void* d_out, int out_size, void* d_ws, size_t ws_size,
                              hipStream_t stream){
  const float* h    = (const float*)d_in[0];
  const int*   idxs = (const int*)d_in[1];
  const float* sw   = (const float*)d_in[2];
  const float* sb   = (const float*)d_in[3];
  const float* trw  = (const float*)d_in[4];
  const float* trb  = (const float*)d_in[5];
  const float* tw1  = (const float*)d_in[6];
  const float* tb1  = (const float*)d_in[7];
  const float* tw2  = (const float*)d_in[8];
  const float* tb2  = (const float*)d_in[9];
  const float* crw  = (const float*)d_in[10];
  const float* crb  = (const float*)d_in[11];
  const float* cw1  = (const float*)d_in[12];
  const float* cb1  = (const float*)d_in[13];
  const float* cw2  = (const float*)d_in[14];
  const float* cb2  = (const float*)d_in[15];
  u16* ws    = (u16*)d_ws;
  float* out = (float*)d_out;
  const int NT = in_sizes[1] / 4;
  const int nh = in_sizes[0];
  const bool useH16 = ws_size >= (size_t)(WS_WELE + nh) * 2;

  hipLaunchKernelGGL(convert_weights, dim3((WS_WELE + 255) / 256), dim3(256), 0, stream,
                     sw, crw, cw1, cw2, trw, tw1, tw2, ws);
  u16* h16 = ws + WS_WELE;
  const int nblk = (NT + 63) / 64;
  if (useH16){
    const int n8 = nh / 8;
    hipLaunchKernelGGL(convert_h, dim3((n8 + 255) / 256), dim3(256), 0, stream, h, h16, n8);
    torsion_kernel<true><<<dim3(nblk), dim3(256), 0, stream>>>(
        h, h16, idxs, sb, crb, cb1, cb2, trb, tb1, tb2, ws, out, NT);
  } else {
    torsion_kernel<false><<<dim3(nblk), dim3(256), 0, stream>>>(
        h, h16, idxs, sb, crb, cb1, cb2, trb, tb1, tb2, ws, out, NT);
  }
}

// Round 18
// 456.108 us; speedup vs baseline: 1.3604x; 1.0055x over previous
//
#include <hip/hip_runtime.h>
#include <stdint.h>

typedef __attribute__((ext_vector_type(8))) short short8;
typedef __attribute__((ext_vector_type(4))) float f32x4;
typedef __attribute__((ext_vector_type(2))) unsigned int u32x2;
typedef unsigned short u16;
typedef unsigned int u32;

#define NPER 6
// WAVE-CONTIGUOUS frag-major weights (bf16 elem offsets). Frag = 512 elems = 1KB.
// Region layout: [wave][ks][4 frags]; fs' = wv*4*NKS + ks*4 + i.
// frag content (lane,j): W[n = (wv*4+i)*16 + (lane&15)][k = ks*32 + (lane>>4)*8 + j]
#define SA_F   0         // 256 frags (NKS=16)
#define CRW_F  131072    // 128 frags (NKS=8)
#define CW1_F  196608
#define CW2_F  262144    // 8 frags, linear (shared by all waves)
#define TRW_F  266240
#define TW1_F  331776
#define TW2_F  397312
#define WS_WELE 401408   // h16 follows

__device__ inline u16 f2b(float f){                 // f32 -> bf16 (RNE) -- converter kernels only
  u32 u = __builtin_bit_cast(u32, f);
  u = u + 0x7FFFu + ((u >> 16) & 1u);
  return (u16)(u >> 16);
}
__device__ inline float elu1(float x){ return x > 0.f ? x : (__expf(x) - 1.f); }
// HW packed f32x2 -> bf16x2 (RNE; bit-identical to f2b -- verified R13/R14 absmax)
__device__ inline u32 cvtpk(float a, float b){
  u32 r;
  asm("v_cvt_pk_bf16_f32 %0, %1, %2" : "=v"(r) : "v"(a), "v"(b));
  return r;
}

// ---- wave-contiguous frag-major weight conversion ----
__global__ __launch_bounds__(256) void convert_weights(
    const float* __restrict__ sw, const float* __restrict__ crw, const float* __restrict__ cw1,
    const float* __restrict__ cw2, const float* __restrict__ trw, const float* __restrict__ tw1,
    const float* __restrict__ tw2, u16* __restrict__ ws){
  int i = blockIdx.x * 256 + threadIdx.x;
  if (i >= WS_WELE) return;
  int e = i & 511;
  int lane = e >> 3, j = e & 7, lr = lane & 15, lg = lane >> 4;
  float v;
  if (i < CRW_F){                                    // sw: 256 frags, NKS=16
    int fs = i >> 9;
    int wv_ = fs >> 6, ks_ = (fs >> 2) & 15, ii_ = fs & 3;
    int n = (wv_ * 4 + ii_) * 16 + lr, k = ks_ * 32 + lg * 8 + j;
    v = sw[n * 512 + k];
  } else if (i < CW2_F || (i >= TRW_F && i < TW2_F)){ // rw/w1 regions: 128 frags, NKS=8
    int base = (i < CW1_F) ? CRW_F : (i < CW2_F) ? CW1_F : (i < TW1_F) ? TRW_F : TW1_F;
    const float* src = (i < CW1_F) ? crw : (i < CW2_F) ? cw1 : (i < TW1_F) ? trw : tw1;
    int fs = (i - base) >> 9;
    int wv_ = fs >> 5, ks_ = (fs >> 2) & 7, ii_ = fs & 3;
    int n = (wv_ * 4 + ii_) * 16 + lr, k = ks_ * 32 + lg * 8 + j;
    v = src[n * 256 + k];
  } else {                                           // w2 pads: 8 frags, linear
    int base = (i < TRW_F) ? CW2_F : TW2_F;
    const float* w2 = (i < TRW_F) ? cw2 : tw2;
    int fs = (i - base) >> 9;
    int k = fs * 32 + lg * 8 + j;
    v = (lr < NPER) ? w2[lr * 256 + k] : 0.f;
  }
  ws[i] = f2b(v);
}

__global__ __launch_bounds__(256) void convert_h(
    const float* __restrict__ h, u16* __restrict__ h16, int n8){
  int i = blockIdx.x * 256 + threadIdx.x;
  if (i >= n8) return;
  const float4* src = (const float4*)(h + (size_t)i * 8);
  float4 q0 = src[0], q1 = src[1];
  short8 v;
  v[0]=(short)f2b(q0.x); v[1]=(short)f2b(q0.y); v[2]=(short)f2b(q0.z); v[3]=(short)f2b(q0.w);
  v[4]=(short)f2b(q1.x); v[5]=(short)f2b(q1.y); v[6]=(short)f2b(q1.z); v[7]=(short)f2b(q1.w);
  *(short8*)(h16 + (size_t)i * 8) = v;
}

// ---- in-kernel macros ----
// W2 frag (linear, shared): unchanged
#define WF(D_, BASE_, FS_) { D_ = ((const short8*)(ws + (BASE_) + (size_t)(FS_) * 512))[lane]; }
// wave-contiguous 4-frag load: one uniform base + imm offsets 0/512/1024/1536 elems
#define WF4(D_, BASE_, KS_, NKS_) { \
  const u16* p_ = ws + (BASE_) + ((size_t)(wv * (NKS_) + (KS_)) * 4) * 512 + lane * 8; \
  D_##0 = *(const short8*)(p_);        D_##1 = *(const short8*)(p_ + 512); \
  D_##2 = *(const short8*)(p_ + 1024); D_##3 = *(const short8*)(p_ + 1536); }
#define LDA4(D_, SRC_, RS_, KB_) { const int ao_ = ((KB_) + lg * 16) ^ aswz; \
  _Pragma("unroll") for (int af_ = 0; af_ < 4; ++af_){ \
    const int r_ = af_ * 16 + lr; \
    D_[af_] = *(const short8*)((SRC_) + r_ * (RS_) + ao_); } }
#define GEMM16(W_, A_) { __builtin_amdgcn_s_setprio(1); \
  _Pragma("unroll") for (int af_ = 0; af_ < 4; ++af_){ \
    acc[0][af_] = __builtin_amdgcn_mfma_f32_16x16x32_bf16(W_##0, A_[af_], acc[0][af_], 0, 0, 0); \
    acc[1][af_] = __builtin_amdgcn_mfma_f32_16x16x32_bf16(W_##1, A_[af_], acc[1][af_], 0, 0, 0); \
    acc[2][af_] = __builtin_amdgcn_mfma_f32_16x16x32_bf16(W_##2, A_[af_], acc[2][af_], 0, 0, 0); \
    acc[3][af_] = __builtin_amdgcn_mfma_f32_16x16x32_bf16(W_##3, A_[af_], acc[3][af_], 0, 0, 0); } \
  __builtin_amdgcn_s_setprio(0); }
// first-k-step variant: C = per-wf bias fragment (replaces zeroing + epilogue bias add)
#define GEMMB16(W_, A_) { __builtin_amdgcn_s_setprio(1); \
  _Pragma("unroll") for (int af_ = 0; af_ < 4; ++af_){ \
    acc[0][af_] = __builtin_amdgcn_mfma_f32_16x16x32_bf16(W_##0, A_[af_], bv[0], 0, 0, 0); \
    acc[1][af_] = __builtin_amdgcn_mfma_f32_16x16x32_bf16(W_##1, A_[af_], bv[1], 0, 0, 0); \
    acc[2][af_] = __builtin_amdgcn_mfma_f32_16x16x32_bf16(W_##2, A_[af_], bv[2], 0, 0, 0); \
    acc[3][af_] = __builtin_amdgcn_mfma_f32_16x16x32_bf16(W_##3, A_[af_], bv[3], 0, 0, 0); } \
  __builtin_amdgcn_s_setprio(0); }
#define LOADBIAS(BP_) { _Pragma("unroll") for (int wf_ = 0; wf_ < 4; ++wf_){ \
    float4 t_ = *(const float4*)((BP_) + wv * 64 + wf_ * 16 + lg * 4); \
    bv[wf_] = (f32x4){t_.x, t_.y, t_.z, t_.w}; } }
#define BAR() { asm volatile("s_waitcnt lgkmcnt(0)" ::: "memory"); \
  __builtin_amdgcn_sched_barrier(0); \
  __builtin_amdgcn_s_barrier(); \
  __builtin_amdgcn_sched_barrier(0); }

// ---- paired-node gather staging (R16): one full node (128 feats, 16KB) per barrier ----
#define LOADC2(sc) { const int sc_ = (sc); \
  int nd_ = (sc_==0)?idx4.x:(sc_==1)?idx4.y:(sc_==2)?idx4.z:idx4.w; \
  if (H16){ const u16* p_ = h16 + (size_t)nd_ * 128 + sq * 32; \
    rgA = *(const short8*)(p_);      rgB = *(const short8*)(p_ + 8); \
    rgC = *(const short8*)(p_ + 16); rgD = *(const short8*)(p_ + 24); } \
  else { const float* fp_ = h + (size_t)nd_ * 128 + sq * 32; \
    float4 qa_=*(const float4*)fp_,      qb_=*(const float4*)(fp_+4); \
    float4 qc_=*(const float4*)(fp_+8),  qd_=*(const float4*)(fp_+12); \
    float4 qe_=*(const float4*)(fp_+16), qf_=*(const float4*)(fp_+20); \
    float4 qg_=*(const float4*)(fp_+24), qh_=*(const float4*)(fp_+28); \
    u32 tA_[4] = { cvtpk(qa_.x,qa_.y), cvtpk(qa_.z,qa_.w), cvtpk(qb_.x,qb_.y), cvtpk(qb_.z,qb_.w) }; \
    u32 tB_[4] = { cvtpk(qc_.x,qc_.y), cvtpk(qc_.z,qc_.w), cvtpk(qd_.x,qd_.y), cvtpk(qd_.z,qd_.w) }; \
    u32 tC_[4] = { cvtpk(qe_.x,qe_.y), cvtpk(qe_.z,qe_.w), cvtpk(qf_.x,qf_.y), cvtpk(qf_.z,qf_.w) }; \
    u32 tD_[4] = { cvtpk(qg_.x,qg_.y), cvtpk(qg_.z,qg_.w), cvtpk(qh_.x,qh_.y), cvtpk(qh_.z,qh_.w) }; \
    rgA = *(short8*)tA_; rgB = *(short8*)tB_; rgC = *(short8*)tC_; rgD = *(short8*)tD_; } }
#define STOREC2(sc) { char* b_ = Zb + (((sc) & 1) << 14) + (sq >> 1) * 8192 + srow * 128; \
  const int o_ = (sq & 1) * 64, sw_ = (srow & 7) << 4; \
  *(short8*)(b_ + ((o_     ) ^ sw_)) = rgA; \
  *(short8*)(b_ + ((o_ + 16) ^ sw_)) = rgB; \
  *(short8*)(b_ + ((o_ + 32) ^ sw_)) = rgC; \
  *(short8*)(b_ + ((o_ + 48) ^ sw_)) = rgD; }

// one 256-k layer (NKS=8), W/A 1-deep prefetch; ks=0 initializes acc with bias (bv)
#define LAYER256B(WBASE_, AB_) { \
  WF4(wfA, WBASE_, 0, 8); \
  LDA4(afA, AB_, 512, 0); \
  _Pragma("unroll") for (int ks_ = 0; ks_ < 8; ++ks_){ \
    if (ks_ & 1){ \
      if (ks_ < 7){ WF4(wfA, WBASE_, ks_ + 1, 8); LDA4(afA, AB_, 512, (ks_ + 1) * 64); } \
      GEMM16(wfB, afB); \
    } else { \
      WF4(wfB, WBASE_, ks_ + 1, 8); LDA4(afB, AB_, 512, (ks_ + 1) * 64); \
      if (ks_ == 0){ GEMMB16(wfA, afA); } else { GEMM16(wfA, afA); } \
    } } }

template<bool H16>
__global__ __launch_bounds__(256) void torsion_kernel(
    const float* __restrict__ h, const u16* __restrict__ h16,
    const int* __restrict__ idxs, const float* __restrict__ sb,
    const float* __restrict__ c_rb, const float* __restrict__ c_b1, const float* __restrict__ c_b2,
    const float* __restrict__ t_rb, const float* __restrict__ t_b1, const float* __restrict__ t_b2,
    const u16* __restrict__ ws, float* __restrict__ out, int NT)
{
  __shared__ __attribute__((aligned(16))) char Xb[32768];   // [64][256] bf16 swizzled
  __shared__ __attribute__((aligned(16))) char Zb[32768];   // gather dbuf 2x16KB, then Y/V

  const int tid = threadIdx.x, blk = blockIdx.x;
  const int lane = tid & 63, lr = lane & 15, lg = lane >> 4;
  const int wv = tid >> 6;                     // wave 0..3 = col quarter
  const int aswz = (lr & 7) << 4;

  const int srow = tid >> 2, sq = tid & 3;
  const int sgrow = blk * 64 + srow;
  int4 idx4 = (sgrow < NT) ? ((const int4*)idxs)[sgrow] : (int4){0, 0, 0, 0};
  short8 rgA, rgB, rgC, rgD;
  short8 wfA0, wfA1, wfA2, wfA3, wfB0, wfB1, wfB2, wfB3;
  short8 afA[4], afB[4];
  f32x4 bv[4];                                 // bias C-fragments (transient per layer)

  f32x4 acc[4][4];

  // ---- prologue: node 0 staged; first W frags + sb bias in flight ----
  LOADC2(0); STOREC2(0);
  WF4(wfA, SA_F, 0, 16);
  LOADBIAS(sb);
  BAR();
  LDA4(afA, Zb, 128, 0);

  // ================ stage A: x = elu(concat(h[idx]) @ sw.T + sb); 4 node-superchunks ================
  #pragma unroll
  for (int sc = 0; sc < 4; ++sc){
    const char* cb = Zb + ((sc & 1) << 14);
    if (sc < 3) LOADC2(sc + 1);                      // next node's loads in flight all interval
    WF4(wfB, SA_F, 4 * sc + 1, 16); LDA4(afB, cb, 128, 64);
    if (sc == 0){ GEMMB16(wfA, afA); } else { GEMM16(wfA, afA); }   // s = 4sc (bias C-init at s=0)
    WF4(wfA, SA_F, 4 * sc + 2, 16); LDA4(afA, cb + 8192, 128, 0);
    GEMM16(wfB, afB);                                // s = 4sc+1
    WF4(wfB, SA_F, 4 * sc + 3, 16); LDA4(afB, cb + 8192, 128, 64);
    GEMM16(wfA, afA);                                // s = 4sc+2
    if (sc < 3) WF4(wfA, SA_F, 4 * sc + 4, 16);
    GEMM16(wfB, afB);                                // s = 4sc+3
    if (sc < 3) STOREC2(sc + 1);
    if (sc == 3){
      // X epilogue: elu (bias already in acc) -> Xb (swizzled bf16)
      #pragma unroll
      for (int wf = 0; wf < 4; ++wf){
        const int col0 = wv * 64 + wf * 16 + lg * 4;
        #pragma unroll
        for (int af = 0; af < 4; ++af){
          const int row = af * 16 + lr;
          u32x2 pk = { cvtpk(elu1(acc[wf][af][0]), elu1(acc[wf][af][1])),
                       cvtpk(elu1(acc[wf][af][2]), elu1(acc[wf][af][3])) };
          *(u32x2*)(Xb + row * 512 + ((col0 * 2) ^ ((row & 7) << 4))) = pk;
        }
      }
    }
    BAR();
    if (sc < 3) LDA4(afA, Zb + (((sc + 1) & 1) << 14), 128, 0);
  }

  // ================ heads: c (score) then t (coeffs) ================
  f32x4 scC = (f32x4){0,0,0,0}, scT = (f32x4){0,0,0,0};
  #pragma unroll
  for (int hd = 0; hd < 2; ++hd){
    const int RWF = hd ? TRW_F : CRW_F;
    const int W1F = hd ? TW1_F : CW1_F;
    const int W2F = hd ? TW2_F : CW2_F;
    const float* RB = hd ? t_rb : c_rb;
    const float* B1 = hd ? t_b1 : c_b1;
    const float* B2 = hd ? t_b2 : c_b2;

    // ---- y = x + elu(x @ rw.T + rb) -> Zb  (rb via C-init; residual re-read from Xb) ----
    LOADBIAS(RB);
    LAYER256B(RWF, Xb);
    #pragma unroll
    for (int wf = 0; wf < 4; ++wf){
      const int col0 = wv * 64 + wf * 16 + lg * 4;
      #pragma unroll
      for (int af = 0; af < 4; ++af){
        const int row = af * 16 + lr;
        const int boff = (col0 * 2) ^ ((row & 7) << 4);
        u32x2 xv = *(const u32x2*)(Xb + row * 512 + boff);
        const float x0 = __builtin_bit_cast(float, xv[0] << 16);
        const float x1 = __builtin_bit_cast(float, xv[0] & 0xffff0000u);
        const float x2 = __builtin_bit_cast(float, xv[1] << 16);
        const float x3 = __builtin_bit_cast(float, xv[1] & 0xffff0000u);
        u32x2 pk = { cvtpk(x0 + elu1(acc[wf][af][0]), x1 + elu1(acc[wf][af][1])),
                     cvtpk(x2 + elu1(acc[wf][af][2]), x3 + elu1(acc[wf][af][3])) };
        *(u32x2*)(Zb + row * 512 + boff) = pk;
      }
    }
    BAR();                                  // Y visible

    // ---- v = elu(y @ w1.T + b1): layer (b1 via C-init), drain-bar, V epilogue -> Zb ----
    LOADBIAS(B1);
    LAYER256B(W1F, Zb);
    BAR();                                  // all Y reads done before overwrite
    #pragma unroll
    for (int wf = 0; wf < 4; ++wf){
      const int col0 = wv * 64 + wf * 16 + lg * 4;
      #pragma unroll
      for (int af = 0; af < 4; ++af){
        const int row = af * 16 + lr;
        u32x2 pk = { cvtpk(elu1(acc[wf][af][0]), elu1(acc[wf][af][1])),
                     cvtpk(elu1(acc[wf][af][2]), elu1(acc[wf][af][3])) };
        *(u32x2*)(Zb + row * 512 + ((col0 * 2) ^ ((row & 7) << 4))) = pk;
      }
    }
    BAR();                                  // V visible

    // ---- out16 = v @ w2p.T: wave wv owns rows wv*16..+15 ----
    {
      f32x4 a1 = (f32x4){0, 0, 0, 0};
      const int vr = wv * 16 + lr;
      const int vswz = (vr & 7) << 4;
      __builtin_amdgcn_s_setprio(1);
      #pragma unroll
      for (int kt = 0; kt < 8; ++kt){
        short8 aw; WF(aw, W2F, kt);
        short8 bv2 = *(const short8*)(Zb + vr * 512 + ((kt * 64 + lg * 16) ^ vswz));
        a1 = __builtin_amdgcn_mfma_f32_16x16x32_bf16(aw, bv2, a1, 0, 0, 0);
      }
      __builtin_amdgcn_s_setprio(0);
      #pragma unroll
      for (int r = 0; r < 4; ++r){
        const int nn = lg * 4 + r;
        a1[r] += (nn < NPER) ? B2[nn] : 0.f;
      }
      if (hd == 0) scC = a1; else scT = a1;
      if (hd == 0) BAR();                   // protect Zb(V) before head t's Y-epilogue overwrite
    }
  }

  // ---- epilogue: score & coeff for row (wv*16+lr) live in this lane ----
  const int grow = blk * 64 + wv * 16 + lr;
  if (grow < NT){
    #pragma unroll
    for (int r = 0; r < 4; ++r){
      const int nn = lg * 4 + r;
      if (nn < NPER){
        const float s = scC[r], c = scT[r];
        out[(size_t)grow * 6 + nn] = s;
        out[(size_t)NT * 6 + (size_t)grow * 6 + nn] = c * 1e-3f * (1.f / (1.f + __expf(-s)));
      }
    }
  }
}

extern "C" void kernel_launch(void* const* d_in, const int* in_sizes, int n_in,
                              void* d_out, int out_size, void* d_ws, size_t ws_size,
                              hipStream_t stream){
  const float* h    = (const float*)d_in[0];
  const int*   idxs = (const int*)d_in[1];
  const float* sw   = (const float*)d_in[2];
  const float* sb   = (const float*)d_in[3];
  const float* trw  = (const float*)d_in[4];
  const float* trb  = (const float*)d_in[5];
  const float* tw1  = (const float*)d_in[6];
  const float* tb1  = (const float*)d_in[7];
  const float* tw2  = (const float*)d_in[8];
  const float* tb2  = (const float*)d_in[9];
  const float* crw  = (const float*)d_in[10];
  const float* crb  = (const float*)d_in[11];
  const float* cw1  = (const float*)d_in[12];
  const float* cb1  = (const float*)d_in[13];
  const float* cw2  = (const float*)d_in[14];
  const float* cb2  = (const float*)d_in[15];
  u16* ws    = (u16*)d_ws;
  float* out = (float*)d_out;
  const int NT = in_sizes[1] / 4;
  const int nh = in_sizes[0];
  const bool useH16 = ws_size >= (size_t)(WS_WELE + nh) * 2;

  hipLaunchKernelGGL(convert_weights, dim3((WS_WELE + 255) / 256), dim3(256), 0, stream,
                     sw, crw, cw1, cw2, trw, tw1, tw2, ws);
  u16* h16 = ws + WS_WELE;
  const int nblk = (NT + 63) / 64;
  if (useH16){
    const int n8 = nh / 8;
    hipLaunchKernelGGL(convert_h, dim3((n8 + 255) / 256), dim3(256), 0, stream, h, h16, n8);
    torsion_kernel<true><<<dim3(nblk), dim3(256), 0, stream>>>(
        h, h16, idxs, sb, crb, cb1, cb2, trb, tb1, tb2, ws, out, NT);
  } else {
    torsion_kernel<false><<<dim3(nblk), dim3(256), 0, stream>>>(
        h, h16, idxs, sb, crb, cb1, cb2, trb, tb1, tb2, ws, out, NT);
  }
}